// Round 1
// baseline (332.559 us; speedup 1.0000x reference)
//
#include <hip/hip_runtime.h>
#include <math.h>

#define EPS 1e-5f

// ---------------- CSR build ----------------
__global__ void k_count(const int* __restrict__ dst, int E, int* __restrict__ cnt){
  int e = blockIdx.x*blockDim.x + threadIdx.x;
  if(e<E) atomicAdd(&cnt[dst[e]], 1);
}

__global__ void k_scan1(const int* __restrict__ cnt, int n, int* __restrict__ bsum){
  __shared__ int red[256];
  int t=threadIdx.x; int i=blockIdx.x*256+t;
  red[t] = (i<n)?cnt[i]:0;
  __syncthreads();
  for(int s=128;s>0;s>>=1){
    if(t<s) red[t]+=red[t+s];
    __syncthreads();
  }
  if(t==0) bsum[blockIdx.x]=red[0];
}

__global__ void k_scan2(const int* __restrict__ bsum, int nb, int* __restrict__ bof){
  if(threadIdx.x==0){
    int acc=0;
    for(int i=0;i<nb;i++){ bof[i]=acc; acc+=bsum[i]; }
  }
}

__global__ void k_scan3(const int* __restrict__ cnt, int n, int E, const int* __restrict__ bof,
                        int* __restrict__ offs, int* __restrict__ cursor, float* __restrict__ dinv){
  __shared__ int red[256];
  int t=threadIdx.x; int i=blockIdx.x*256+t;
  int v = (i<n)?cnt[i]:0;
  red[t]=v; __syncthreads();
  for(int s=1;s<256;s<<=1){
    int a = (t>=s)?red[t-s]:0;
    __syncthreads();
    red[t]+=a;
    __syncthreads();
  }
  if(i<n){
    int o = bof[blockIdx.x] + red[t]-v;   // exclusive prefix
    offs[i]=o; cursor[i]=o;
    dinv[i]=rsqrtf((float)v + 1.0f);      // deg = in-count + 1 (self loop)
  }
  if(i==0 && blockIdx.x==0) offs[n]=E;
}

__global__ void k_scatter(const int* __restrict__ src, const int* __restrict__ dst, int E,
                          int* __restrict__ cursor, int* __restrict__ csr){
  int e = blockIdx.x*blockDim.x + threadIdx.x;
  if(e<E){
    int d = dst[e];
    int p = atomicAdd(&cursor[d],1);
    csr[p] = src[e];
  }
}

// ---------------- edge aggregation on x (pre-GEMM, linearity) ----------------
// one wave per dst node; lane holds float2 (features 2l, 2l+1)
__global__ void k_agg(const float2* __restrict__ x2, const int* __restrict__ offs,
                      const int* __restrict__ csr, const float* __restrict__ dinv,
                      int n, float2* __restrict__ z2){
  int w = (blockIdx.x*blockDim.x + threadIdx.x)>>6;
  int lane = threadIdx.x & 63;
  if(w>=n) return;
  float dd = dinv[w];
  float2 xv = x2[w*64 + lane];
  float sc = dd*dd;
  float ax = xv.x*sc, ay = xv.y*sc;
  int k = offs[w], k1 = offs[w+1];
  for(; k+3 < k1; k+=4){
    int s0=csr[k], s1=csr[k+1], s2=csr[k+2], s3=csr[k+3];
    float c0=dinv[s0]*dd, c1=dinv[s1]*dd, c2=dinv[s2]*dd, c3=dinv[s3]*dd;
    float2 v0=x2[s0*64+lane], v1=x2[s1*64+lane], v2=x2[s2*64+lane], v3=x2[s3*64+lane];
    ax += c0*v0.x; ay += c0*v0.y;
    ax += c1*v1.x; ay += c1*v1.y;
    ax += c2*v2.x; ay += c2*v2.y;
    ax += c3*v3.x; ay += c3*v3.y;
  }
  for(; k<k1; k++){
    int s=csr[k]; float c=dinv[s]*dd; float2 v=x2[s*64+lane];
    ax += c*v.x; ay += c*v.y;
  }
  z2[w*64+lane] = make_float2(ax,ay);
}

// ---------------- fused z@W + bias + ReLU + LayerNorm ----------------
// 64 rows/block, 256 threads, thread tile 8 rows x 4 cols. W read from global (L2-hot).
// NOTE: hn may alias z (all z reads staged to LDS before first barrier; stores after).
__global__ __launch_bounds__(256) void k_gemmln(
    const float* z, const float* __restrict__ W,
    const float* __restrict__ bgc, const float* __restrict__ gamma, const float* __restrict__ beta,
    int n, float* hn){
  __shared__ float zt[128][68];     // [k][r], pad 68: b128 reads aligned, stage writes 4-way max
  __shared__ float rsum[64][33];
  __shared__ float rsq[64][33];
  __shared__ float mu_s[64], is_s[64];
  int t = threadIdx.x;
  int rowBase = blockIdx.x*64;
  for(int i=0;i<32;i++){
    int idx = i*256 + t;
    int r = idx>>7, c = idx&127;
    zt[c][r] = (rowBase+r < n) ? z[(size_t)(rowBase+r)*128 + c] : 0.f;
  }
  __syncthreads();
  int cg = t & 31, rg = t >> 5;
  int c0 = cg*4, r0 = rg*8;
  float acc[8][4];
  #pragma unroll
  for(int i=0;i<8;i++){ acc[i][0]=0.f; acc[i][1]=0.f; acc[i][2]=0.f; acc[i][3]=0.f; }
  #pragma unroll 4
  for(int k=0;k<128;k++){
    float4 wv = *(const float4*)(W + k*128 + c0);
    float4 za = *(const float4*)(&zt[k][r0]);
    float4 zb = *(const float4*)(&zt[k][r0+4]);
    acc[0][0]+=za.x*wv.x; acc[0][1]+=za.x*wv.y; acc[0][2]+=za.x*wv.z; acc[0][3]+=za.x*wv.w;
    acc[1][0]+=za.y*wv.x; acc[1][1]+=za.y*wv.y; acc[1][2]+=za.y*wv.z; acc[1][3]+=za.y*wv.w;
    acc[2][0]+=za.z*wv.x; acc[2][1]+=za.z*wv.y; acc[2][2]+=za.z*wv.z; acc[2][3]+=za.z*wv.w;
    acc[3][0]+=za.w*wv.x; acc[3][1]+=za.w*wv.y; acc[3][2]+=za.w*wv.z; acc[3][3]+=za.w*wv.w;
    acc[4][0]+=zb.x*wv.x; acc[4][1]+=zb.x*wv.y; acc[4][2]+=zb.x*wv.z; acc[4][3]+=zb.x*wv.w;
    acc[5][0]+=zb.y*wv.x; acc[5][1]+=zb.y*wv.y; acc[5][2]+=zb.y*wv.z; acc[5][3]+=zb.y*wv.w;
    acc[6][0]+=zb.z*wv.x; acc[6][1]+=zb.z*wv.y; acc[6][2]+=zb.z*wv.z; acc[6][3]+=zb.z*wv.w;
    acc[7][0]+=zb.w*wv.x; acc[7][1]+=zb.w*wv.y; acc[7][2]+=zb.w*wv.z; acc[7][3]+=zb.w*wv.w;
  }
  float4 bb = *(const float4*)(bgc + c0);
  float bbv[4] = {bb.x, bb.y, bb.z, bb.w};
  #pragma unroll
  for(int i=0;i<8;i++){
    float s=0.f, q=0.f;
    #pragma unroll
    for(int j=0;j<4;j++){
      float v = acc[i][j] + bbv[j];
      v = fmaxf(v, 0.f);
      acc[i][j]=v; s+=v; q+=v*v;
    }
    rsum[r0+i][cg]=s; rsq[r0+i][cg]=q;
  }
  __syncthreads();
  if(t<64){
    float s=0.f,q=0.f;
    for(int j=0;j<32;j++){ s+=rsum[t][j]; q+=rsq[t][j]; }
    float mu = s*(1.f/128.f);
    float var = q*(1.f/128.f) - mu*mu;
    mu_s[t]=mu; is_s[t]=rsqrtf(var+EPS);
  }
  __syncthreads();
  float4 gm = *(const float4*)(gamma + c0);
  float4 bt = *(const float4*)(beta + c0);
  #pragma unroll
  for(int i=0;i<8;i++){
    int r = r0+i;
    if(rowBase+r >= n) continue;
    float m = mu_s[r], scl = is_s[r];
    float4 o;
    o.x = (acc[i][0]-m)*scl*gm.x + bt.x;
    o.y = (acc[i][1]-m)*scl*gm.y + bt.y;
    o.z = (acc[i][2]-m)*scl*gm.z + bt.z;
    o.w = (acc[i][3]-m)*scl*gm.w + bt.w;
    *(float4*)(hn + (size_t)(rowBase+r)*128 + c0) = o;
  }
}

// ---------------- pooling + MLP head, one block per graph ----------------
__device__ __forceinline__ int lbound(const int* __restrict__ a, int n, int key){
  int lo=0, hi=n;
  while(lo<hi){ int mid=(lo+hi)>>1; if(a[mid]<key) lo=mid+1; else hi=mid; }
  return lo;
}

__global__ void k_head(const float* __restrict__ hn, const int* __restrict__ batch, int n,
                       const float* __restrict__ W1, const float* __restrict__ b1,
                       const float* __restrict__ W2, const float* __restrict__ b2,
                       const float* __restrict__ W3, const float* __restrict__ b3,
                       float* __restrict__ out){
  int g = blockIdx.x, t = threadIdx.x;
  __shared__ float red[2][128];
  __shared__ float gl[384];
  __shared__ float h1[128];
  __shared__ float h2[64];
  int start = lbound(batch,n,g), end = lbound(batch,n,g+1);
  int cnt = end-start;
  int f = t & 127, half = t >> 7;
  float sum=0.f, mx=-3.402823466e38f;
  for(int node=start+half; node<end; node+=2){
    float v = hn[(size_t)node*128+f];
    sum += v; mx = fmaxf(mx,v);
  }
  red[half][f]=sum;
  __syncthreads();
  if(t<128){
    float s = red[0][t]+red[1][t];
    gl[128+t]=s;                                  // add pool
    gl[t]= s / (float)((cnt>1)?cnt:1);            // mean pool
  }
  __syncthreads();
  red[half][f]=mx;
  __syncthreads();
  if(t<128){
    float m = fmaxf(red[0][t],red[1][t]);
    gl[256+t] = (cnt>0)? m : 0.f;                 // max pool
  }
  __syncthreads();
  // MLP layer 1: [384]->[128]
  int j = t & 127, kh = t >> 7;
  float p=0.f;
  for(int k=kh*192; k<kh*192+192; k++) p += gl[k]*W1[k*128+j];
  red[kh][j]=p;
  __syncthreads();
  if(t<128){
    float v = red[0][t]+red[1][t]+b1[t];
    h1[t]=fmaxf(v,0.f);
  }
  __syncthreads();
  // MLP layer 2: [128]->[64]
  if(t<64){
    float a=b2[t];
    for(int k=0;k<128;k++) a += h1[k]*W2[k*64+t];
    h2[t]=fmaxf(a,0.f);
  }
  __syncthreads();
  // MLP layer 3: [64]->[10]
  if(t<10){
    float a=b3[t];
    for(int k=0;k<64;k++) a += h2[k]*W3[k*10+t];
    out[g*10+t]=a;
  }
}

extern "C" void kernel_launch(void* const* d_in, const int* in_sizes, int n_in,
                              void* d_out, int out_size, void* d_ws, size_t ws_size,
                              hipStream_t stream){
  const float* x     = (const float*)d_in[0];
  const int*   ei    = (const int*)d_in[1];
  const int*   batch = (const int*)d_in[2];
  const float* Wg    = (const float*)d_in[4];
  const float* bg    = (const float*)d_in[5];
  const float* gamma = (const float*)d_in[6];
  const float* beta  = (const float*)d_in[7];
  const float* W1    = (const float*)d_in[8];
  const float* b1    = (const float*)d_in[9];
  const float* W2    = (const float*)d_in[10];
  const float* b2    = (const float*)d_in[11];
  const float* W3    = (const float*)d_in[12];
  const float* b3    = (const float*)d_in[13];
  float* out = (float*)d_out;

  int N = in_sizes[0]/128;
  int E = in_sizes[1]/2;
  const int G = 64;                 // num_graphs (fixed problem shape)
  const int* src = ei;
  const int* dst = ei + E;

  char* p = (char*)d_ws;
  auto alloc=[&](size_t bytes)->char*{ char* r=p; p += (bytes+255)&~(size_t)255; return r; };
  int*   cnt    = (int*)  alloc((size_t)N*4);
  int*   offs   = (int*)  alloc((size_t)(N+1)*4);
  int*   cursor = (int*)  alloc((size_t)N*4);
  float* dinv   = (float*)alloc((size_t)N*4);
  int*   bsum   = (int*)  alloc(1024);
  int*   bof    = (int*)  alloc(1024);
  int*   csr    = (int*)  alloc((size_t)E*4);
  float* z      = (float*)alloc((size_t)N*128*4);   // aggregated x; then overwritten by hn in-place

  hipMemsetAsync(cnt, 0, (size_t)N*4, stream);
  int eb = (E+255)/256;
  int nb = (N+255)/256;
  k_count  <<<eb,256,0,stream>>>(dst,E,cnt);
  k_scan1  <<<nb,256,0,stream>>>(cnt,N,bsum);
  k_scan2  <<<1,64,0,stream>>>(bsum,nb,bof);
  k_scan3  <<<nb,256,0,stream>>>(cnt,N,E,bof,offs,cursor,dinv);
  k_scatter<<<eb,256,0,stream>>>(src,dst,E,cursor,csr);
  int ab = (int)(((size_t)N*64 + 255)/256);
  k_agg    <<<ab,256,0,stream>>>((const float2*)x,offs,csr,dinv,N,(float2*)z);
  k_gemmln <<<(N+63)/64,256,0,stream>>>(z,Wg,bg,gamma,beta,N,z);
  k_head   <<<G,256,0,stream>>>(z,batch,N,W1,b1,W2,b2,W3,b3,out);
}

// Round 2
// 260.338 us; speedup vs baseline: 1.2774x; 1.2774x over previous
//
#include <hip/hip_runtime.h>
#include <math.h>

#define EPS 1e-5f
#define FLT_BIG 3.402823466e38f

// ---- float<->monotone-u32 mapping for atomicMax on floats ----
__device__ __forceinline__ unsigned fflip(float f){
  int i = __float_as_int(f);
  return (unsigned)(i ^ ((i>>31) | 0x80000000));
}
__device__ __forceinline__ float funflip(unsigned u){
  int i = (u & 0x80000000u) ? (int)(u ^ 0x80000000u) : (int)(~u);
  return __int_as_float(i);
}

// ---------------- CSR build ----------------
__global__ void k_count(const int* __restrict__ dst, int E, int* __restrict__ cnt){
  int e = blockIdx.x*blockDim.x + threadIdx.x;
  if(e<E) atomicAdd(&cnt[dst[e]], 1);
}

__global__ void k_scan1(const int* __restrict__ cnt, int n, int* __restrict__ bsum){
  __shared__ int red[256];
  int t=threadIdx.x; int i=blockIdx.x*256+t;
  red[t] = (i<n)?cnt[i]:0;
  __syncthreads();
  for(int s=128;s>0;s>>=1){
    if(t<s) red[t]+=red[t+s];
    __syncthreads();
  }
  if(t==0) bsum[blockIdx.x]=red[0];
}

__global__ void k_scan2(const int* __restrict__ bsum, int nb, int* __restrict__ bof){
  if(threadIdx.x==0){
    int acc=0;
    for(int i=0;i<nb;i++){ bof[i]=acc; acc+=bsum[i]; }
  }
}

__global__ void k_scan3(const int* __restrict__ cnt, int n, int E, const int* __restrict__ bof,
                        int* __restrict__ offs, int* __restrict__ cursor, float* __restrict__ dinv){
  __shared__ int red[256];
  int t=threadIdx.x; int i=blockIdx.x*256+t;
  int v = (i<n)?cnt[i]:0;
  red[t]=v; __syncthreads();
  for(int s=1;s<256;s<<=1){
    int a = (t>=s)?red[t-s]:0;
    __syncthreads();
    red[t]+=a;
    __syncthreads();
  }
  if(i<n){
    int o = bof[blockIdx.x] + red[t]-v;   // exclusive prefix
    offs[i]=o; cursor[i]=o;
    dinv[i]=rsqrtf((float)v + 1.0f);      // deg = in-count + 1 (self loop)
  }
  if(i==0 && blockIdx.x==0) offs[n]=E;
}

__global__ void k_scatter(const int* __restrict__ src, const int* __restrict__ dst, int E,
                          int* __restrict__ cursor, int* __restrict__ csr){
  int e = blockIdx.x*blockDim.x + threadIdx.x;
  if(e<E){
    int d = dst[e];
    int p = atomicAdd(&cursor[d],1);
    csr[p] = src[e];
  }
}

// ---------------- edge aggregation on x (pre-GEMM, linearity) ----------------
// one wave per dst node; lane holds float2 (features 2l, 2l+1)
__global__ void k_agg(const float2* __restrict__ x2, const int* __restrict__ offs,
                      const int* __restrict__ csr, const float* __restrict__ dinv,
                      int n, float2* __restrict__ z2){
  int w = (blockIdx.x*blockDim.x + threadIdx.x)>>6;
  int lane = threadIdx.x & 63;
  if(w>=n) return;
  float dd = dinv[w];
  float2 xv = x2[w*64 + lane];
  float sc = dd*dd;
  float ax = xv.x*sc, ay = xv.y*sc;
  int k = offs[w], k1 = offs[w+1];
  for(; k+3 < k1; k+=4){
    int s0=csr[k], s1=csr[k+1], s2=csr[k+2], s3=csr[k+3];
    float c0=dinv[s0]*dd, c1=dinv[s1]*dd, c2=dinv[s2]*dd, c3=dinv[s3]*dd;
    float2 v0=x2[s0*64+lane], v1=x2[s1*64+lane], v2=x2[s2*64+lane], v3=x2[s3*64+lane];
    ax += c0*v0.x; ay += c0*v0.y;
    ax += c1*v1.x; ay += c1*v1.y;
    ax += c2*v2.x; ay += c2*v2.y;
    ax += c3*v3.x; ay += c3*v3.y;
  }
  for(; k<k1; k++){
    int s=csr[k]; float c=dinv[s]*dd; float2 v=x2[s*64+lane];
    ax += c*v.x; ay += c*v.y;
  }
  z2[w*64+lane] = make_float2(ax,ay);
}

// ---------------- fused z@W + bias + ReLU + LayerNorm + pool-reduce ----------------
// 64 rows/block, 256 threads, thread tile 8 rows x 4 cols. W read from global (L2-hot).
// LN output never hits global: per-graph block-level reduce in LDS, then one
// atomicAdd + one atomicMax(u32) per (graph,col) per block.
__global__ __launch_bounds__(256) void k_gemmln(
    const float* __restrict__ z, const float* __restrict__ W,
    const float* __restrict__ bgc, const float* __restrict__ gamma, const float* __restrict__ beta,
    const int* __restrict__ batch, int n,
    float* __restrict__ pool_sum, unsigned* __restrict__ pool_maxu){
  __shared__ float zt[128][68];     // [k][r]
  __shared__ float rsum[64][33];    // reused as ps[8][128] for pooling
  __shared__ float rsq[64][33];     // reused as pm[8][128] for pooling
  __shared__ float mu_s[64], is_s[64];
  __shared__ int gb[64];
  int t = threadIdx.x;
  int rowBase = blockIdx.x*64;
  for(int i=0;i<32;i++){
    int idx = i*256 + t;
    int r = idx>>7, c = idx&127;
    zt[c][r] = (rowBase+r < n) ? z[(size_t)(rowBase+r)*128 + c] : 0.f;
  }
  if(t<64) gb[t] = (rowBase+t < n) ? batch[rowBase+t] : -1;
  __syncthreads();
  int cg = t & 31, rg = t >> 5;
  int c0 = cg*4, r0 = rg*8;
  float acc[8][4];
  #pragma unroll
  for(int i=0;i<8;i++){ acc[i][0]=0.f; acc[i][1]=0.f; acc[i][2]=0.f; acc[i][3]=0.f; }
  #pragma unroll 4
  for(int k=0;k<128;k++){
    float4 wv = *(const float4*)(W + k*128 + c0);
    float4 za = *(const float4*)(&zt[k][r0]);
    float4 zb = *(const float4*)(&zt[k][r0+4]);
    acc[0][0]+=za.x*wv.x; acc[0][1]+=za.x*wv.y; acc[0][2]+=za.x*wv.z; acc[0][3]+=za.x*wv.w;
    acc[1][0]+=za.y*wv.x; acc[1][1]+=za.y*wv.y; acc[1][2]+=za.y*wv.z; acc[1][3]+=za.y*wv.w;
    acc[2][0]+=za.z*wv.x; acc[2][1]+=za.z*wv.y; acc[2][2]+=za.z*wv.z; acc[2][3]+=za.z*wv.w;
    acc[3][0]+=za.w*wv.x; acc[3][1]+=za.w*wv.y; acc[3][2]+=za.w*wv.z; acc[3][3]+=za.w*wv.w;
    acc[4][0]+=zb.x*wv.x; acc[4][1]+=zb.x*wv.y; acc[4][2]+=zb.x*wv.z; acc[4][3]+=zb.x*wv.w;
    acc[5][0]+=zb.y*wv.x; acc[5][1]+=zb.y*wv.y; acc[5][2]+=zb.y*wv.z; acc[5][3]+=zb.y*wv.w;
    acc[6][0]+=zb.z*wv.x; acc[6][1]+=zb.z*wv.y; acc[6][2]+=zb.z*wv.z; acc[6][3]+=zb.z*wv.w;
    acc[7][0]+=zb.w*wv.x; acc[7][1]+=zb.w*wv.y; acc[7][2]+=zb.w*wv.z; acc[7][3]+=zb.w*wv.w;
  }
  float4 bb = *(const float4*)(bgc + c0);
  float bbv[4] = {bb.x, bb.y, bb.z, bb.w};
  #pragma unroll
  for(int i=0;i<8;i++){
    float s=0.f, q=0.f;
    #pragma unroll
    for(int j=0;j<4;j++){
      float v = acc[i][j] + bbv[j];
      v = fmaxf(v, 0.f);
      acc[i][j]=v; s+=v; q+=v*v;
    }
    rsum[r0+i][cg]=s; rsq[r0+i][cg]=q;
  }
  __syncthreads();
  if(t<64){
    float s=0.f,q=0.f;
    for(int j=0;j<32;j++){ s+=rsum[t][j]; q+=rsq[t][j]; }
    float mu = s*(1.f/128.f);
    float var = q*(1.f/128.f) - mu*mu;
    mu_s[t]=mu; is_s[t]=rsqrtf(var+EPS);
  }
  __syncthreads();
  float4 gm = *(const float4*)(gamma + c0);
  float4 bt = *(const float4*)(beta + c0);
  #pragma unroll
  for(int i=0;i<8;i++){
    int r = r0+i;
    float m = mu_s[r], scl = is_s[r];
    acc[i][0] = (acc[i][0]-m)*scl*gm.x + bt.x;
    acc[i][1] = (acc[i][1]-m)*scl*gm.y + bt.y;
    acc[i][2] = (acc[i][2]-m)*scl*gm.z + bt.z;
    acc[i][3] = (acc[i][3]-m)*scl*gm.w + bt.w;
  }
  // ---- per-graph block reduce + global atomics ----
  int last = min(63, n-1-rowBase);
  float* ps = &rsum[0][0];   // [8][128]
  float* pm = &rsq[0][0];    // [8][128]
  // gb already synced above; gmin/gmax from LDS
  int gmin = gb[0], gmax = gb[last];
  if(gmin < 0) gmin = 0;
  if(gmax < gmin) gmax = gmin;
  for(int g=gmin; g<=gmax; ++g){
    float4 s4 = make_float4(0.f,0.f,0.f,0.f);
    float4 m4 = make_float4(-FLT_BIG,-FLT_BIG,-FLT_BIG,-FLT_BIG);
    #pragma unroll
    for(int i=0;i<8;i++){
      if(gb[r0+i]==g){
        s4.x += acc[i][0]; s4.y += acc[i][1]; s4.z += acc[i][2]; s4.w += acc[i][3];
        m4.x = fmaxf(m4.x, acc[i][0]); m4.y = fmaxf(m4.y, acc[i][1]);
        m4.z = fmaxf(m4.z, acc[i][2]); m4.w = fmaxf(m4.w, acc[i][3]);
      }
    }
    __syncthreads();   // protect LDS reuse (prev iter / LN-stats reads done)
    *(float4*)(ps + rg*128 + c0) = s4;
    *(float4*)(pm + rg*128 + c0) = m4;
    __syncthreads();
    if(t<128){
      float ss=0.f, mm=-FLT_BIG;
      #pragma unroll
      for(int i2=0;i2<8;i2++){ ss += ps[i2*128+t]; mm = fmaxf(mm, pm[i2*128+t]); }
      if(ss != 0.f) atomicAdd(&pool_sum[g*128+t], ss);
      if(mm > -FLT_BIG) atomicMax(&pool_maxu[g*128+t], fflip(mm));
    }
  }
}

// ---------------- MLP head, one block per graph (pools precomputed) ----------------
__device__ __forceinline__ int lbound(const int* __restrict__ a, int n, int key){
  int lo=0, hi=n;
  while(lo<hi){ int mid=(lo+hi)>>1; if(a[mid]<key) lo=mid+1; else hi=mid; }
  return lo;
}

__global__ void k_head(const float* __restrict__ pool_sum, const unsigned* __restrict__ pool_maxu,
                       const int* __restrict__ batch, int n,
                       const float* __restrict__ W1, const float* __restrict__ b1,
                       const float* __restrict__ W2, const float* __restrict__ b2,
                       const float* __restrict__ W3, const float* __restrict__ b3,
                       float* __restrict__ out){
  int g = blockIdx.x, t = threadIdx.x;
  __shared__ float red[2][128];
  __shared__ float gl[384];
  __shared__ float h1[128];
  __shared__ float h2[64];
  __shared__ int cnt_s;
  if(t==0){
    int s = lbound(batch,n,g), e = lbound(batch,n,g+1);
    cnt_s = e - s;
  }
  __syncthreads();
  int cnt = cnt_s;
  if(t<128){
    float s = pool_sum[g*128+t];
    gl[128+t] = s;                                    // add pool
    gl[t] = s / (float)((cnt>1)?cnt:1);               // mean pool
    float m = funflip(pool_maxu[g*128+t]);
    gl[256+t] = (cnt>0) ? m : 0.f;                    // max pool
  }
  __syncthreads();
  // MLP layer 1: [384]->[128]
  int j = t & 127, kh = t >> 7;
  float p=0.f;
  for(int k=kh*192; k<kh*192+192; k++) p += gl[k]*W1[k*128+j];
  red[kh][j]=p;
  __syncthreads();
  if(t<128){
    float v = red[0][t]+red[1][t]+b1[t];
    h1[t]=fmaxf(v,0.f);
  }
  __syncthreads();
  // MLP layer 2: [128]->[64]
  if(t<64){
    float a=b2[t];
    for(int k=0;k<128;k++) a += h1[k]*W2[k*64+t];
    h2[t]=fmaxf(a,0.f);
  }
  __syncthreads();
  // MLP layer 3: [64]->[10]
  if(t<10){
    float a=b3[t];
    for(int k=0;k<64;k++) a += h2[k]*W3[k*10+t];
    out[g*10+t]=a;
  }
}

extern "C" void kernel_launch(void* const* d_in, const int* in_sizes, int n_in,
                              void* d_out, int out_size, void* d_ws, size_t ws_size,
                              hipStream_t stream){
  const float* x     = (const float*)d_in[0];
  const int*   ei    = (const int*)d_in[1];
  const int*   batch = (const int*)d_in[2];
  const float* Wg    = (const float*)d_in[4];
  const float* bg    = (const float*)d_in[5];
  const float* gamma = (const float*)d_in[6];
  const float* beta  = (const float*)d_in[7];
  const float* W1    = (const float*)d_in[8];
  const float* b1    = (const float*)d_in[9];
  const float* W2    = (const float*)d_in[10];
  const float* b2    = (const float*)d_in[11];
  const float* W3    = (const float*)d_in[12];
  const float* b3    = (const float*)d_in[13];
  float* out = (float*)d_out;

  int N = in_sizes[0]/128;
  int E = in_sizes[1]/2;
  const int G = 64;                 // num_graphs (fixed problem shape)
  const int* src = ei;
  const int* dst = ei + E;

  char* p = (char*)d_ws;
  auto alloc=[&](size_t bytes)->char*{ char* r=p; p += (bytes+255)&~(size_t)255; return r; };
  int*      cnt    = (int*)     alloc((size_t)N*4);
  int*      offs   = (int*)     alloc((size_t)(N+1)*4);
  int*      cursor = (int*)     alloc((size_t)N*4);
  float*    dinv   = (float*)   alloc((size_t)N*4);
  int*      bsum   = (int*)     alloc(1024);
  int*      bof    = (int*)     alloc(1024);
  int*      csr    = (int*)     alloc((size_t)E*4);
  float*    z      = (float*)   alloc((size_t)N*128*4);
  float*    psum   = (float*)   alloc((size_t)G*128*4);
  unsigned* pmaxu  = (unsigned*)alloc((size_t)G*128*4);

  hipMemsetAsync(cnt, 0, (size_t)N*4, stream);
  hipMemsetAsync(psum, 0, (size_t)G*128*4, stream);
  hipMemsetAsync(pmaxu, 0, (size_t)G*128*4, stream);
  int eb = (E+255)/256;
  int nb = (N+255)/256;
  k_count  <<<eb,256,0,stream>>>(dst,E,cnt);
  k_scan1  <<<nb,256,0,stream>>>(cnt,N,bsum);
  k_scan2  <<<1,64,0,stream>>>(bsum,nb,bof);
  k_scan3  <<<nb,256,0,stream>>>(cnt,N,E,bof,offs,cursor,dinv);
  k_scatter<<<eb,256,0,stream>>>(src,dst,E,cursor,csr);
  int ab = (int)(((size_t)N*64 + 255)/256);
  k_agg    <<<ab,256,0,stream>>>((const float2*)x,offs,csr,dinv,N,(float2*)z);
  k_gemmln <<<(N+63)/64,256,0,stream>>>(z,Wg,bg,gamma,beta,batch,N,psum,pmaxu);
  k_head   <<<G,256,0,stream>>>(psum,pmaxu,batch,N,W1,b1,W2,b2,W3,b3,out);
}

// Round 3
// 247.856 us; speedup vs baseline: 1.3417x; 1.0504x over previous
//
#include <hip/hip_runtime.h>
#include <math.h>

#define EPS 1e-5f
#define FLT_BIG 3.402823466e38f

// ---- float<->monotone-u32 mapping for atomicMax on floats ----
__device__ __forceinline__ unsigned fflip(float f){
  int i = __float_as_int(f);
  return (unsigned)(i ^ ((i>>31) | 0x80000000));
}
__device__ __forceinline__ float funflip(unsigned u){
  int i = (u & 0x80000000u) ? (int)(u ^ 0x80000000u) : (int)(~u);
  return __int_as_float(i);
}

__device__ __forceinline__ unsigned short f2bf(float f){
  unsigned u = __float_as_uint(f);
  unsigned r = (u + 0x7FFFu + ((u>>16)&1u)) >> 16;
  return (unsigned short)r;
}
__device__ __forceinline__ float bf_lo(unsigned v){ return __uint_as_float(v<<16); }
__device__ __forceinline__ float bf_hi(unsigned v){ return __uint_as_float(v & 0xFFFF0000u); }

// ---------------- x fp32 -> bf16 (packed 2/uint) ----------------
__global__ void k_cast(const float4* __restrict__ x4, unsigned long long nq,
                       ushort4* __restrict__ xb4){
  unsigned long long i = (unsigned long long)blockIdx.x*blockDim.x + threadIdx.x;
  if(i<nq){
    float4 v = x4[i];
    ushort4 o;
    o.x = f2bf(v.x); o.y = f2bf(v.y); o.z = f2bf(v.z); o.w = f2bf(v.w);
    xb4[i] = o;
  }
}

// ---------------- CSR build ----------------
__global__ void k_count(const int* __restrict__ dst, int E, int* __restrict__ cnt){
  int e = blockIdx.x*blockDim.x + threadIdx.x;
  if(e<E) atomicAdd(&cnt[dst[e]], 1);
}

__global__ void k_scan1(const int* __restrict__ cnt, int n, int* __restrict__ bsum){
  __shared__ int red[256];
  int t=threadIdx.x; int i=blockIdx.x*256+t;
  red[t] = (i<n)?cnt[i]:0;
  __syncthreads();
  for(int s=128;s>0;s>>=1){
    if(t<s) red[t]+=red[t+s];
    __syncthreads();
  }
  if(t==0) bsum[blockIdx.x]=red[0];
}

__global__ void k_scan2(const int* __restrict__ bsum, int nb, int* __restrict__ bof){
  if(threadIdx.x==0){
    int acc=0;
    for(int i=0;i<nb;i++){ bof[i]=acc; acc+=bsum[i]; }
  }
}

__global__ void k_scan3(const int* __restrict__ cnt, int n, int E, const int* __restrict__ bof,
                        int* __restrict__ offs, int* __restrict__ cursor, float* __restrict__ dinv){
  __shared__ int red[256];
  int t=threadIdx.x; int i=blockIdx.x*256+t;
  int v = (i<n)?cnt[i]:0;
  red[t]=v; __syncthreads();
  for(int s=1;s<256;s<<=1){
    int a = (t>=s)?red[t-s]:0;
    __syncthreads();
    red[t]+=a;
    __syncthreads();
  }
  if(i<n){
    int o = bof[blockIdx.x] + red[t]-v;   // exclusive prefix
    offs[i]=o; cursor[i]=o;
    dinv[i]=rsqrtf((float)v + 1.0f);      // deg = in-count + 1 (self loop)
  }
  if(i==0 && blockIdx.x==0) offs[n]=E;
}

__global__ void k_scatter(const int* __restrict__ src, const int* __restrict__ dst, int E,
                          int* __restrict__ cursor, int* __restrict__ csr){
  int e = blockIdx.x*blockDim.x + threadIdx.x;
  if(e<E){
    int d = dst[e];
    int p = atomicAdd(&cursor[d],1);
    csr[p] = src[e];
  }
}

// ---------------- edge aggregation on bf16 x (pre-GEMM, linearity) ----------------
// one wave per dst node; lane holds 2 features packed in one uint (bf16x2)
__global__ void k_agg(const unsigned* __restrict__ xb, const int* __restrict__ offs,
                      const int* __restrict__ csr, const float* __restrict__ dinv,
                      int n, float2* __restrict__ z2){
  int w = (blockIdx.x*blockDim.x + threadIdx.x)>>6;
  int lane = threadIdx.x & 63;
  if(w>=n) return;
  float dd = dinv[w];
  unsigned vs = xb[w*64 + lane];
  float sc = dd*dd;
  float ax = bf_lo(vs)*sc, ay = bf_hi(vs)*sc;
  int k = offs[w], k1 = offs[w+1];
  for(; k+3 < k1; k+=4){
    int s0=csr[k], s1=csr[k+1], s2=csr[k+2], s3=csr[k+3];
    float c0=dinv[s0]*dd, c1=dinv[s1]*dd, c2=dinv[s2]*dd, c3=dinv[s3]*dd;
    unsigned v0=xb[s0*64+lane], v1=xb[s1*64+lane], v2=xb[s2*64+lane], v3=xb[s3*64+lane];
    ax += c0*bf_lo(v0); ay += c0*bf_hi(v0);
    ax += c1*bf_lo(v1); ay += c1*bf_hi(v1);
    ax += c2*bf_lo(v2); ay += c2*bf_hi(v2);
    ax += c3*bf_lo(v3); ay += c3*bf_hi(v3);
  }
  for(; k<k1; k++){
    int s=csr[k]; float c=dinv[s]*dd; unsigned v=xb[s*64+lane];
    ax += c*bf_lo(v); ay += c*bf_hi(v);
  }
  z2[w*64+lane] = make_float2(ax,ay);
}

// ---------------- fused z@W + bias + ReLU + LayerNorm + pool-reduce ----------------
__global__ __launch_bounds__(256) void k_gemmln(
    const float* __restrict__ z, const float* __restrict__ W,
    const float* __restrict__ bgc, const float* __restrict__ gamma, const float* __restrict__ beta,
    const int* __restrict__ batch, int n,
    float* __restrict__ pool_sum, unsigned* __restrict__ pool_maxu){
  __shared__ float zt[128][68];     // [k][r]
  __shared__ float rsum[64][33];    // reused as ps[8][128] for pooling
  __shared__ float rsq[64][33];     // reused as pm[8][128] for pooling
  __shared__ float mu_s[64], is_s[64];
  __shared__ int gb[64];
  int t = threadIdx.x;
  int rowBase = blockIdx.x*64;
  for(int i=0;i<32;i++){
    int idx = i*256 + t;
    int r = idx>>7, c = idx&127;
    zt[c][r] = (rowBase+r < n) ? z[(size_t)(rowBase+r)*128 + c] : 0.f;
  }
  if(t<64) gb[t] = (rowBase+t < n) ? batch[rowBase+t] : -1;
  __syncthreads();
  int cg = t & 31, rg = t >> 5;
  int c0 = cg*4, r0 = rg*8;
  float acc[8][4];
  #pragma unroll
  for(int i=0;i<8;i++){ acc[i][0]=0.f; acc[i][1]=0.f; acc[i][2]=0.f; acc[i][3]=0.f; }
  #pragma unroll 4
  for(int k=0;k<128;k++){
    float4 wv = *(const float4*)(W + k*128 + c0);
    float4 za = *(const float4*)(&zt[k][r0]);
    float4 zb = *(const float4*)(&zt[k][r0+4]);
    acc[0][0]+=za.x*wv.x; acc[0][1]+=za.x*wv.y; acc[0][2]+=za.x*wv.z; acc[0][3]+=za.x*wv.w;
    acc[1][0]+=za.y*wv.x; acc[1][1]+=za.y*wv.y; acc[1][2]+=za.y*wv.z; acc[1][3]+=za.y*wv.w;
    acc[2][0]+=za.z*wv.x; acc[2][1]+=za.z*wv.y; acc[2][2]+=za.z*wv.z; acc[2][3]+=za.z*wv.w;
    acc[3][0]+=za.w*wv.x; acc[3][1]+=za.w*wv.y; acc[3][2]+=za.w*wv.z; acc[3][3]+=za.w*wv.w;
    acc[4][0]+=zb.x*wv.x; acc[4][1]+=zb.x*wv.y; acc[4][2]+=zb.x*wv.z; acc[4][3]+=zb.x*wv.w;
    acc[5][0]+=zb.y*wv.x; acc[5][1]+=zb.y*wv.y; acc[5][2]+=zb.y*wv.z; acc[5][3]+=zb.y*wv.w;
    acc[6][0]+=zb.z*wv.x; acc[6][1]+=zb.z*wv.y; acc[6][2]+=zb.z*wv.z; acc[6][3]+=zb.z*wv.w;
    acc[7][0]+=zb.w*wv.x; acc[7][1]+=zb.w*wv.y; acc[7][2]+=zb.w*wv.z; acc[7][3]+=zb.w*wv.w;
  }
  float4 bb = *(const float4*)(bgc + c0);
  float bbv[4] = {bb.x, bb.y, bb.z, bb.w};
  #pragma unroll
  for(int i=0;i<8;i++){
    float s=0.f, q=0.f;
    #pragma unroll
    for(int j=0;j<4;j++){
      float v = acc[i][j] + bbv[j];
      v = fmaxf(v, 0.f);
      acc[i][j]=v; s+=v; q+=v*v;
    }
    rsum[r0+i][cg]=s; rsq[r0+i][cg]=q;
  }
  __syncthreads();
  if(t<64){
    float s=0.f,q=0.f;
    for(int j=0;j<32;j++){ s+=rsum[t][j]; q+=rsq[t][j]; }
    float mu = s*(1.f/128.f);
    float var = q*(1.f/128.f) - mu*mu;
    mu_s[t]=mu; is_s[t]=rsqrtf(var+EPS);
  }
  __syncthreads();
  float4 gm = *(const float4*)(gamma + c0);
  float4 bt = *(const float4*)(beta + c0);
  #pragma unroll
  for(int i=0;i<8;i++){
    int r = r0+i;
    float m = mu_s[r], scl = is_s[r];
    acc[i][0] = (acc[i][0]-m)*scl*gm.x + bt.x;
    acc[i][1] = (acc[i][1]-m)*scl*gm.y + bt.y;
    acc[i][2] = (acc[i][2]-m)*scl*gm.z + bt.z;
    acc[i][3] = (acc[i][3]-m)*scl*gm.w + bt.w;
  }
  // ---- per-graph block reduce + global atomics ----
  int last = min(63, n-1-rowBase);
  float* ps = &rsum[0][0];   // [8][128]
  float* pm = &rsq[0][0];    // [8][128]
  int gmin = gb[0], gmax = gb[last];
  if(gmin < 0) gmin = 0;
  if(gmax < gmin) gmax = gmin;
  for(int g=gmin; g<=gmax; ++g){
    float4 s4 = make_float4(0.f,0.f,0.f,0.f);
    float4 m4 = make_float4(-FLT_BIG,-FLT_BIG,-FLT_BIG,-FLT_BIG);
    #pragma unroll
    for(int i=0;i<8;i++){
      if(gb[r0+i]==g){
        s4.x += acc[i][0]; s4.y += acc[i][1]; s4.z += acc[i][2]; s4.w += acc[i][3];
        m4.x = fmaxf(m4.x, acc[i][0]); m4.y = fmaxf(m4.y, acc[i][1]);
        m4.z = fmaxf(m4.z, acc[i][2]); m4.w = fmaxf(m4.w, acc[i][3]);
      }
    }
    __syncthreads();
    *(float4*)(ps + rg*128 + c0) = s4;
    *(float4*)(pm + rg*128 + c0) = m4;
    __syncthreads();
    if(t<128){
      float ss=0.f, mm=-FLT_BIG;
      #pragma unroll
      for(int i2=0;i2<8;i2++){ ss += ps[i2*128+t]; mm = fmaxf(mm, pm[i2*128+t]); }
      if(ss != 0.f) atomicAdd(&pool_sum[g*128+t], ss);
      if(mm > -FLT_BIG) atomicMax(&pool_maxu[g*128+t], fflip(mm));
    }
  }
}

// ---------------- MLP head, one block per graph (pools precomputed) ----------------
__device__ __forceinline__ int lbound(const int* __restrict__ a, int n, int key){
  int lo=0, hi=n;
  while(lo<hi){ int mid=(lo+hi)>>1; if(a[mid]<key) lo=mid+1; else hi=mid; }
  return lo;
}

__global__ void k_head(const float* __restrict__ pool_sum, const unsigned* __restrict__ pool_maxu,
                       const int* __restrict__ batch, int n,
                       const float* __restrict__ W1, const float* __restrict__ b1,
                       const float* __restrict__ W2, const float* __restrict__ b2,
                       const float* __restrict__ W3, const float* __restrict__ b3,
                       float* __restrict__ out){
  int g = blockIdx.x, t = threadIdx.x;
  __shared__ float red[2][128];
  __shared__ float gl[384];
  __shared__ float h1[128];
  __shared__ float h2[64];
  __shared__ int cnt_s;
  if(t==0){
    int s = lbound(batch,n,g), e = lbound(batch,n,g+1);
    cnt_s = e - s;
  }
  __syncthreads();
  int cnt = cnt_s;
  if(t<128){
    float s = pool_sum[g*128+t];
    gl[128+t] = s;                                    // add pool
    gl[t] = s / (float)((cnt>1)?cnt:1);               // mean pool
    float m = funflip(pool_maxu[g*128+t]);
    gl[256+t] = (cnt>0) ? m : 0.f;                    // max pool
  }
  __syncthreads();
  // MLP layer 1: [384]->[128]
  int j = t & 127, kh = t >> 7;
  float p=0.f;
  for(int k=kh*192; k<kh*192+192; k++) p += gl[k]*W1[k*128+j];
  red[kh][j]=p;
  __syncthreads();
  if(t<128){
    float v = red[0][t]+red[1][t]+b1[t];
    h1[t]=fmaxf(v,0.f);
  }
  __syncthreads();
  // MLP layer 2: [128]->[64]
  if(t<64){
    float a=b2[t];
    for(int k=0;k<128;k++) a += h1[k]*W2[k*64+t];
    h2[t]=fmaxf(a,0.f);
  }
  __syncthreads();
  // MLP layer 3: [64]->[10]
  if(t<10){
    float a=b3[t];
    for(int k=0;k<64;k++) a += h2[k]*W3[k*10+t];
    out[g*10+t]=a;
  }
}

extern "C" void kernel_launch(void* const* d_in, const int* in_sizes, int n_in,
                              void* d_out, int out_size, void* d_ws, size_t ws_size,
                              hipStream_t stream){
  const float* x     = (const float*)d_in[0];
  const int*   ei    = (const int*)d_in[1];
  const int*   batch = (const int*)d_in[2];
  const float* Wg    = (const float*)d_in[4];
  const float* bg    = (const float*)d_in[5];
  const float* gamma = (const float*)d_in[6];
  const float* beta  = (const float*)d_in[7];
  const float* W1    = (const float*)d_in[8];
  const float* b1    = (const float*)d_in[9];
  const float* W2    = (const float*)d_in[10];
  const float* b2    = (const float*)d_in[11];
  const float* W3    = (const float*)d_in[12];
  const float* b3    = (const float*)d_in[13];
  float* out = (float*)d_out;

  int N = in_sizes[0]/128;
  int E = in_sizes[1]/2;
  const int G = 64;                 // num_graphs (fixed problem shape)
  const int* src = ei;
  const int* dst = ei + E;

  char* p = (char*)d_ws;
  auto alloc=[&](size_t bytes)->char*{ char* r=p; p += (bytes+255)&~(size_t)255; return r; };
  int*      cnt    = (int*)     alloc((size_t)N*4);
  int*      offs   = (int*)     alloc((size_t)(N+1)*4);
  int*      cursor = (int*)     alloc((size_t)N*4);
  float*    dinv   = (float*)   alloc((size_t)N*4);
  int*      bsum   = (int*)     alloc(1024);
  int*      bof    = (int*)     alloc(1024);
  int*      csr    = (int*)     alloc((size_t)E*4);
  float*    z      = (float*)   alloc((size_t)N*128*4);
  float*    psum   = (float*)   alloc((size_t)G*128*4);
  unsigned* pmaxu  = (unsigned*)alloc((size_t)G*128*4);
  unsigned* xb     = (unsigned*)alloc((size_t)N*128*2);   // bf16 x

  hipMemsetAsync(cnt, 0, (size_t)N*4, stream);
  hipMemsetAsync(psum, 0, (size_t)G*128*4, stream);
  hipMemsetAsync(pmaxu, 0, (size_t)G*128*4, stream);
  int eb = (E+255)/256;
  int nb = (N+255)/256;
  unsigned long long nq = (unsigned long long)N*32;   // float4 quads
  k_cast   <<<(int)((nq+255)/256),256,0,stream>>>((const float4*)x, nq, (ushort4*)xb);
  k_count  <<<eb,256,0,stream>>>(dst,E,cnt);
  k_scan1  <<<nb,256,0,stream>>>(cnt,N,bsum);
  k_scan2  <<<1,64,0,stream>>>(bsum,nb,bof);
  k_scan3  <<<nb,256,0,stream>>>(cnt,N,E,bof,offs,cursor,dinv);
  k_scatter<<<eb,256,0,stream>>>(src,dst,E,cursor,csr);
  int ab = (int)(((size_t)N*64 + 255)/256);
  k_agg    <<<ab,256,0,stream>>>(xb,offs,csr,dinv,N,(float2*)z);
  k_gemmln <<<(N+63)/64,256,0,stream>>>(z,Wg,bg,gamma,beta,batch,N,psum,pmaxu);
  k_head   <<<G,256,0,stream>>>(psum,pmaxu,batch,N,W1,b1,W2,b2,W3,b3,out);
}